// Round 4
// baseline (3434.647 us; speedup 1.0000x reference)
//
#include <hip/hip_runtime.h>
#include <hip/hip_bf16.h>
#include <math.h>

// B=2, T=32, H=32, W=32, HID=64, IN=384, OUT=384, L=1024, rows=65536
// h5 layout: [b][c][t][l] -> b*2097152 + c*32768 + t*1024 + l
// OUTPUT IS FLOAT32 (reference returns fp32; bf16 writes were the r1-r3 bug:
// bit-identical absmax 7.77 > max|ref| = packed-pair misread signature)
// ws layout (float offsets): gf[128] @0, bnp[256] @128, h5 @1024,
// a1 @4195328, a2 @8389632, x3(bf16) @12583936. total = 58.7 MB

#define OFF_GF 0
#define OFF_BN 128
#define OFF_H5 1024
#define OFF_A1 4195328
#define OFF_A2 8389632
#define OFF_X3 12583936

__device__ __forceinline__ float gelu_f(float v) {
    return 0.5f * v * (1.0f + erff(v * 0.70710678118654752f));
}

// ---------------------------------------------------------------------------
// K0: g = ifft_T(fw), F = ifft_T(fb) (T=32). gf: gr[32] gi[32] Fr[32] Fi[32]
// ---------------------------------------------------------------------------
__global__ __launch_bounds__(64) void k0_prep(const float* __restrict__ fw,
                                              const float* __restrict__ fb,
                                              float* __restrict__ gf) {
    int tid = threadIdx.x;
    if (tid < 32) {
        float gr = 0.f, gi = 0.f, Fr = 0.f, Fi = 0.f;
        for (int f = 0; f < 32; f++) {
            int ph = (f * tid) & 31;
            float ang = 6.283185307179586f * (float)ph * (1.0f / 32.0f);
            float s, c;
            __sincosf(ang, &s, &c);
            float wv = fw[f], bv = fb[f];
            gr += wv * c; gi += wv * s;
            Fr += bv * c; Fi += bv * s;
        }
        const float inv = 1.0f / 32.0f;
        gf[tid]      = gr * inv;
        gf[32 + tid] = gi * inv;
        gf[64 + tid] = Fr * inv;
        gf[96 + tid] = Fi * inv;
    }
}

// ---------------------------------------------------------------------------
// K1: down GEMM + bias + GELU -> h5 (channel-planar)
// 512 blocks x 128 thr; 128 rows x 64 ch per block; 8x8 per thread.
// ---------------------------------------------------------------------------
__global__ __launch_bounds__(128) void k1_down(const float* __restrict__ x,
                                               const float* __restrict__ dw,
                                               const float* __restrict__ db,
                                               float* __restrict__ h5) {
    __shared__ float xs[128 * 36];
    __shared__ float wsh[64 * 36];
    const int tid = threadIdx.x;
    const int row0 = blockIdx.x * 128;
    const int cg = tid & 7;
    const int rg = tid >> 3;

    float acc[8][8];
#pragma unroll
    for (int i = 0; i < 8; i++)
#pragma unroll
        for (int j = 0; j < 8; j++) acc[i][j] = 0.f;

    for (int kc = 0; kc < 384; kc += 32) {
#pragma unroll
        for (int i = 0; i < 8; i++) {
            int q = tid + i * 128;
            int r = q >> 3, kq = q & 7;
            float4 v = *(const float4*)(x + (row0 + r) * 384 + kc + kq * 4);
            *(float4*)(xs + r * 36 + kq * 4) = v;
        }
#pragma unroll
        for (int i = 0; i < 4; i++) {
            int q = tid + i * 128;
            int c = q >> 3, kq = q & 7;
            float4 v = *(const float4*)(dw + c * 384 + kc + kq * 4);
            *(float4*)(wsh + c * 36 + kq * 4) = v;
        }
        __syncthreads();
#pragma unroll
        for (int kq = 0; kq < 8; kq++) {
            float4 xv[8], wv[8];
#pragma unroll
            for (int j = 0; j < 8; j++)
                xv[j] = *(const float4*)(xs + (rg + 16 * j) * 36 + kq * 4);
#pragma unroll
            for (int i = 0; i < 8; i++)
                wv[i] = *(const float4*)(wsh + (cg + 8 * i) * 36 + kq * 4);
#pragma unroll
            for (int i = 0; i < 8; i++)
#pragma unroll
                for (int j = 0; j < 8; j++)
                    acc[i][j] += wv[i].x * xv[j].x + wv[i].y * xv[j].y +
                                 wv[i].z * xv[j].z + wv[i].w * xv[j].w;
        }
        __syncthreads();
    }

#pragma unroll
    for (int i = 0; i < 8; i++) {
        int c = cg + 8 * i;
        float bias = db[c];
#pragma unroll
        for (int j = 0; j < 8; j++) {
            int r = row0 + rg + 16 * j;
            int b = r >> 15;
            int t = (r >> 10) & 31;
            int l = r & 1023;
            h5[b * 2097152 + c * 32768 + t * 1024 + l] = gelu_f(acc[i][j] + bias);
        }
    }
}

// ---------------------------------------------------------------------------
// K2a: spatial depthwise (1,3,3) pad1 & (1,5,5) pad2 per (b,c,t) plane.
// 4096 blocks x 256 thr.
// ---------------------------------------------------------------------------
__global__ __launch_bounds__(256) void k2a_spatial(const float* __restrict__ h5,
                                                   const float* __restrict__ k31w,
                                                   const float* __restrict__ k31b,
                                                   const float* __restrict__ k51w,
                                                   const float* __restrict__ k51b,
                                                   float* __restrict__ a1,
                                                   float* __restrict__ a2) {
    __shared__ float pl[32 * 33];
    __shared__ float w3[9];
    __shared__ float w5[25];
    const int tid = threadIdx.x;
    const int bct = blockIdx.x;
    const int base = bct << 10;
    const int c = (bct >> 5) & 63;

#pragma unroll
    for (int i = 0; i < 4; i++) {
        int l = tid + i * 256;
        pl[(l >> 5) * 33 + (l & 31)] = h5[base + l];
    }
    if (tid < 9)  w3[tid] = k31w[c * 9 + tid];
    if (tid < 25) w5[tid] = k51w[c * 25 + tid];
    float b3 = k31b[c], b5 = k51b[c];
    __syncthreads();

#pragma unroll
    for (int i = 0; i < 4; i++) {
        int l = tid + i * 256;
        int h = l >> 5, w = l & 31;
        float s3 = b3;
#pragma unroll
        for (int dh = -1; dh <= 1; dh++) {
            int hh = h + dh;
            if (hh < 0 || hh > 31) continue;
#pragma unroll
            for (int dwi = -1; dwi <= 1; dwi++) {
                int ww = w + dwi;
                if (ww < 0 || ww > 31) continue;
                s3 += pl[hh * 33 + ww] * w3[(dh + 1) * 3 + dwi + 1];
            }
        }
        float s5 = b5;
#pragma unroll
        for (int dh = -2; dh <= 2; dh++) {
            int hh = h + dh;
            if (hh < 0 || hh > 31) continue;
#pragma unroll
            for (int dwi = -2; dwi <= 2; dwi++) {
                int ww = w + dwi;
                if (ww < 0 || ww > 31) continue;
                s5 += pl[hh * 33 + ww] * w5[(dh + 2) * 5 + dwi + 2];
            }
        }
        a1[base + l] = s3;
        a2[base + l] = s5;
    }
}

// ---------------------------------------------------------------------------
// K2b: FFT branch = complex circular conv along T (+ ifft(fb) delta at l==0),
// magnitude -> x3 (bf16). 512 blocks x 256 thr.
// ---------------------------------------------------------------------------
__global__ __launch_bounds__(256) void k2b_fft(const float* __restrict__ h5,
                                               __hip_bfloat16* __restrict__ x3,
                                               const float* __restrict__ gf) {
    __shared__ float col[32 * 256];
    __shared__ float gfs[128];
    const int tid = threadIdx.x;
    const int bid = blockIdx.x;
    const int bc = bid >> 2;
    const int l = (bid & 3) * 256 + tid;
    const int base = bc * 32768 + l;

    if (tid < 128) gfs[tid] = gf[tid];
#pragma unroll
    for (int t = 0; t < 32; t++) col[t * 256 + tid] = h5[base + t * 1024];
    __syncthreads();

    const bool dc = (l == 0);
    for (int t = 0; t < 32; t++) {
        float ar = dc ? gfs[64 + t] : 0.f;
        float ai = dc ? gfs[96 + t] : 0.f;
#pragma unroll
        for (int d = 0; d < 32; d++) {
            float xv = col[(((t - d) & 31) << 8) + tid];
            ar += xv * gfs[d];
            ai += xv * gfs[32 + d];
        }
        x3[base + t * 1024] = __float2bfloat16(sqrtf(ar * ar + ai * ai));
    }
}

// ---------------------------------------------------------------------------
// K2c: temporal depthwise convs (3,1,1) pad1 / (5,1,1) pad2, in-place a1/a2.
// 512 blocks x 256 thr; one T-column per thread.
// ---------------------------------------------------------------------------
__global__ __launch_bounds__(256) void k2c_temporal(float* __restrict__ a1,
                                                    float* __restrict__ a2,
                                                    const float* __restrict__ k32w,
                                                    const float* __restrict__ k32b,
                                                    const float* __restrict__ k52w,
                                                    const float* __restrict__ k52b) {
    const int cid = blockIdx.x * 256 + threadIdx.x;
    const int bc = cid >> 10;
    const int l = cid & 1023;
    const int c = bc & 63;
    const int base = bc * 32768 + l;

    float a[32];
#pragma unroll
    for (int t = 0; t < 32; t++) a[t] = a1[base + t * 1024];
    {
        float w0 = k32w[c * 3], w1 = k32w[c * 3 + 1], w2 = k32w[c * 3 + 2];
        float bb = k32b[c];
#pragma unroll
        for (int t = 0; t < 32; t++) {
            float v = bb + a[t] * w1;
            if (t > 0)  v += a[t - 1] * w0;
            if (t < 31) v += a[t + 1] * w2;
            a1[base + t * 1024] = v;
        }
    }
#pragma unroll
    for (int t = 0; t < 32; t++) a[t] = a2[base + t * 1024];
    {
        float u0 = k52w[c * 5], u1 = k52w[c * 5 + 1], u2 = k52w[c * 5 + 2];
        float u3 = k52w[c * 5 + 3], u4 = k52w[c * 5 + 4];
        float bb = k52b[c];
#pragma unroll
        for (int t = 0; t < 32; t++) {
            float v = bb + a[t] * u2;
            if (t > 1)  v += a[t - 2] * u0;
            if (t > 0)  v += a[t - 1] * u1;
            if (t < 31) v += a[t + 1] * u3;
            if (t < 30) v += a[t + 2] * u4;
            a2[base + t * 1024] = v;
        }
    }
}

// ---------------------------------------------------------------------------
// K2d: deterministic BN stats + finalize. One block per channel (64 x 256).
// ---------------------------------------------------------------------------
__global__ __launch_bounds__(256) void k2d_bn(const float* __restrict__ a1,
                                              const float* __restrict__ a2,
                                              const float* __restrict__ g3,
                                              const float* __restrict__ b3,
                                              const float* __restrict__ g5,
                                              const float* __restrict__ b5,
                                              float* __restrict__ bnp) {
    __shared__ float r0[256], r1[256], r2[256], r3[256];
    const int tid = threadIdx.x;
    const int c = blockIdx.x;
    float s1 = 0.f, q1 = 0.f, s2 = 0.f, q2 = 0.f;
#pragma unroll
    for (int b = 0; b < 2; b++) {
        const int base = b * 2097152 + c * 32768;
        for (int i = tid * 4; i < 32768; i += 1024) {
            float4 v1 = *(const float4*)(a1 + base + i);
            float4 v2 = *(const float4*)(a2 + base + i);
            s1 += v1.x + v1.y + v1.z + v1.w;
            q1 += v1.x * v1.x + v1.y * v1.y + v1.z * v1.z + v1.w * v1.w;
            s2 += v2.x + v2.y + v2.z + v2.w;
            q2 += v2.x * v2.x + v2.y * v2.y + v2.z * v2.z + v2.w * v2.w;
        }
    }
    r0[tid] = s1; r1[tid] = q1; r2[tid] = s2; r3[tid] = q2;
    __syncthreads();
    for (int s = 128; s > 0; s >>= 1) {
        if (tid < s) {
            r0[tid] += r0[tid + s];
            r1[tid] += r1[tid + s];
            r2[tid] += r2[tid + s];
            r3[tid] += r3[tid + s];
        }
        __syncthreads();
    }
    if (tid == 0) {
        const float inv_n = 1.0f / 65536.0f;
        float m1 = r0[0] * inv_n;
        float v1 = r1[0] * inv_n - m1 * m1;
        float sc1 = g3[c] * rsqrtf(v1 + 1e-5f);
        float m2 = r2[0] * inv_n;
        float v2 = r3[0] * inv_n - m2 * m2;
        float sc2 = g5[c] * rsqrtf(v2 + 1e-5f);
        bnp[c] = sc1;
        bnp[64 + c] = b3[c] - m1 * sc1;
        bnp[128 + c] = sc2;
        bnp[192 + c] = b5[c] - m2 * sc2;
    }
}

// ---------------------------------------------------------------------------
// K4: s = relu(bn(a1)) + relu(bn(a2)) + x3; attn = cw@s + cb; h5 += attn.
// 512 blocks x 256 thr; 128 positions x 64 ch per block.
// ---------------------------------------------------------------------------
__global__ __launch_bounds__(256) void k4_pointwise(float* __restrict__ h5,
                                                    const float* __restrict__ a1,
                                                    const float* __restrict__ a2,
                                                    const __hip_bfloat16* __restrict__ x3,
                                                    const float* __restrict__ cw,
                                                    const float* __restrict__ cb,
                                                    const float* __restrict__ bnp) {
    __shared__ float ls[64 * 129];
    __shared__ float cs[64 * 64];
    __shared__ float cbs[64];
    __shared__ float bns[256];
    const int tid = threadIdx.x;
    const int pos0 = blockIdx.x * 128;
    const int b = pos0 >> 15;
    const int rem = pos0 & 32767;
    const int t = rem >> 10;
    const int l0 = rem & 1023;
    const int pbase = b * 2097152 + t * 1024 + l0;

#pragma unroll
    for (int i = 0; i < 16; i++) cs[tid + i * 256] = cw[tid + i * 256];
    if (tid < 64) cbs[tid] = cb[tid];
    bns[tid] = bnp[tid];
    __syncthreads();

#pragma unroll
    for (int i = 0; i < 32; i++) {
        int q = tid + i * 256;
        int c = q >> 7, l = q & 127;
        int idx = pbase + c * 32768 + l;
        float v1 = fmaxf(bns[c] * a1[idx] + bns[64 + c], 0.f);
        float v2 = fmaxf(bns[128 + c] * a2[idx] + bns[192 + c], 0.f);
        ls[c * 129 + l] = v1 + v2 + __bfloat162float(x3[idx]);
    }
    __syncthreads();

    const int lidx = tid & 127;
    const int og = tid >> 7;
    float sreg[64];
#pragma unroll
    for (int c = 0; c < 64; c++) sreg[c] = ls[c * 129 + lidx];
    float acc[32];
#pragma unroll
    for (int oi = 0; oi < 32; oi++) acc[oi] = cbs[og * 32 + oi];
#pragma unroll
    for (int cq = 0; cq < 16; cq++) {
        float s0 = sreg[cq * 4], s1 = sreg[cq * 4 + 1];
        float s2 = sreg[cq * 4 + 2], s3 = sreg[cq * 4 + 3];
#pragma unroll
        for (int oi = 0; oi < 32; oi++) {
            float4 wv = *(const float4*)(cs + (og * 32 + oi) * 64 + cq * 4);
            acc[oi] += wv.x * s0 + wv.y * s1 + wv.z * s2 + wv.w * s3;
        }
    }
#pragma unroll
    for (int oi = 0; oi < 32; oi++) {
        int o = og * 32 + oi;
        int idx = pbase + o * 32768 + lidx;
        h5[idx] = h5[idx] + acc[oi];
    }
}

// ---------------------------------------------------------------------------
// K5: up GEMM + bias + GELU + residual -> FLOAT32 out.
// grid (3, 1024) x 256 thr; 64 rows x 128 cols per block; 8x4 per thread.
// ---------------------------------------------------------------------------
__global__ __launch_bounds__(256) void k5_up(const float* __restrict__ y5,
                                             const float* __restrict__ uw,
                                             const float* __restrict__ ub,
                                             const float* __restrict__ x,
                                             float* __restrict__ out) {
    __shared__ float ys[64 * 65];
    __shared__ float wts[128 * 68];
    const int tid = threadIdx.x;
    const int row0 = blockIdx.y * 64;
    const int c0 = blockIdx.x * 128;
    const int b = row0 >> 15;
    const int t = (row0 >> 10) & 31;
    const int l0 = row0 & 1023;
    const int ybase = b * 2097152 + t * 1024 + l0;

#pragma unroll
    for (int i = 0; i < 16; i++) {
        int q = tid + i * 256;
        int k = q >> 6, l = q & 63;
        ys[k * 65 + l] = y5[ybase + k * 32768 + l];
    }
#pragma unroll
    for (int i = 0; i < 32; i++) {
        int q = tid + i * 256;
        int c = q >> 6, k = q & 63;
        wts[c * 68 + k] = uw[(c0 + c) * 64 + k];
    }
    __syncthreads();

    const int cg = tid & 31;
    const int rg = tid >> 5;
    float acc[8][4];
#pragma unroll
    for (int j = 0; j < 8; j++)
#pragma unroll
        for (int ci = 0; ci < 4; ci++) acc[j][ci] = 0.f;

#pragma unroll
    for (int kq = 0; kq < 16; kq++) {
        float4 wv[4];
#pragma unroll
        for (int ci = 0; ci < 4; ci++)
            wv[ci] = *(const float4*)(wts + (cg + 32 * ci) * 68 + kq * 4);
#pragma unroll
        for (int kk = 0; kk < 4; kk++) {
            int k = kq * 4 + kk;
            float yv[8];
#pragma unroll
            for (int j = 0; j < 8; j++) yv[j] = ys[k * 65 + rg + 8 * j];
#pragma unroll
            for (int ci = 0; ci < 4; ci++) {
                const float* wp = (const float*)&wv[ci];
                float wk = wp[kk];
#pragma unroll
                for (int j = 0; j < 8; j++) acc[j][ci] += yv[j] * wk;
            }
        }
    }

#pragma unroll
    for (int ci = 0; ci < 4; ci++) {
        int c = c0 + cg + 32 * ci;
        float ubv = ub[c];
#pragma unroll
        for (int j = 0; j < 8; j++) {
            int row = row0 + rg + 8 * j;
            float v = gelu_f(acc[j][ci] + ubv);
            out[row * 384 + c] = x[row * 384 + c] + v;
        }
    }
}

// ---------------------------------------------------------------------------
extern "C" void kernel_launch(void* const* d_in, const int* in_sizes, int n_in,
                              void* d_out, int out_size, void* d_ws, size_t ws_size,
                              hipStream_t stream) {
    const float* x      = (const float*)d_in[0];
    const float* down_w = (const float*)d_in[1];
    const float* down_b = (const float*)d_in[2];
    const float* k31w   = (const float*)d_in[3];
    const float* k31b   = (const float*)d_in[4];
    const float* k32w   = (const float*)d_in[5];
    const float* k32b   = (const float*)d_in[6];
    const float* bn3g   = (const float*)d_in[7];
    const float* bn3b   = (const float*)d_in[8];
    const float* k51w   = (const float*)d_in[9];
    const float* k51b   = (const float*)d_in[10];
    const float* k52w   = (const float*)d_in[11];
    const float* k52b   = (const float*)d_in[12];
    const float* bn5g   = (const float*)d_in[13];
    const float* bn5b   = (const float*)d_in[14];
    const float* conv_w = (const float*)d_in[15];
    const float* conv_b = (const float*)d_in[16];
    const float* fw     = (const float*)d_in[17];
    const float* fb     = (const float*)d_in[18];
    const float* up_w   = (const float*)d_in[19];
    const float* up_b   = (const float*)d_in[20];
    float* out = (float*)d_out;

    float* wsf = (float*)d_ws;
    float* gfb = wsf + OFF_GF;
    float* bnp = wsf + OFF_BN;
    float* h5  = wsf + OFF_H5;
    float* a1  = wsf + OFF_A1;
    float* a2  = wsf + OFF_A2;
    __hip_bfloat16* x3 = (__hip_bfloat16*)(wsf + OFF_X3);

    k0_prep<<<1, 64, 0, stream>>>(fw, fb, gfb);
    k1_down<<<512, 128, 0, stream>>>(x, down_w, down_b, h5);
    k2a_spatial<<<4096, 256, 0, stream>>>(h5, k31w, k31b, k51w, k51b, a1, a2);
    k2b_fft<<<512, 256, 0, stream>>>(h5, x3, gfb);
    k2c_temporal<<<512, 256, 0, stream>>>(a1, a2, k32w, k32b, k52w, k52b);
    k2d_bn<<<64, 256, 0, stream>>>(a1, a2, bn3g, bn3b, bn5g, bn5b, bnp);
    k4_pointwise<<<512, 256, 0, stream>>>(h5, a1, a2, x3, conv_w, conv_b, bnp);
    k5_up<<<dim3(3, 1024), 256, 0, stream>>>(h5, up_w, up_b, x, out);
}

// Round 5
// 718.714 us; speedup vs baseline: 4.7789x; 4.7789x over previous
//
#include <hip/hip_runtime.h>
#include <hip/hip_bf16.h>
#include <math.h>

// B=2, T=32, H=32, W=32, HID=64, IN=384, OUT=384, L=1024, rows=65536
// h5 layout: [b][c][t][l] -> b*2097152 + c*32768 + t*1024 + l
// OUTPUT IS FLOAT32 (reference returns fp32).
// ws layout (float offsets): gf[128] @0, bnp[256] @128, h5 @1024,
// a1 @4195328, a2 @8389632, x3(bf16) @12583936. total = 58.7 MB

#define OFF_GF 0
#define OFF_BN 128
#define OFF_H5 1024
#define OFF_A1 4195328
#define OFF_A2 8389632
#define OFF_X3 12583936

__device__ __forceinline__ float gelu_f(float v) {
    return 0.5f * v * (1.0f + erff(v * 0.70710678118654752f));
}

// ---------------------------------------------------------------------------
// K0: g = ifft_T(fw), F = ifft_T(fb) (T=32). gf: gr[32] gi[32] Fr[32] Fi[32]
// ---------------------------------------------------------------------------
__global__ __launch_bounds__(64) void k0_prep(const float* __restrict__ fw,
                                              const float* __restrict__ fb,
                                              float* __restrict__ gf) {
    int tid = threadIdx.x;
    if (tid < 32) {
        float gr = 0.f, gi = 0.f, Fr = 0.f, Fi = 0.f;
        for (int f = 0; f < 32; f++) {
            int ph = (f * tid) & 31;
            float ang = 6.283185307179586f * (float)ph * (1.0f / 32.0f);
            float s, c;
            __sincosf(ang, &s, &c);
            float wv = fw[f], bv = fb[f];
            gr += wv * c; gi += wv * s;
            Fr += bv * c; Fi += bv * s;
        }
        const float inv = 1.0f / 32.0f;
        gf[tid]      = gr * inv;
        gf[32 + tid] = gi * inv;
        gf[64 + tid] = Fr * inv;
        gf[96 + tid] = Fi * inv;
    }
}

// ---------------------------------------------------------------------------
// K1: down GEMM + bias + GELU -> h5 (channel-planar)
// 512 blocks x 128 thr; 128 rows x 64 ch per block; 8x8 per thread.
// ---------------------------------------------------------------------------
__global__ __launch_bounds__(128) void k1_down(const float* __restrict__ x,
                                               const float* __restrict__ dw,
                                               const float* __restrict__ db,
                                               float* __restrict__ h5) {
    __shared__ float xs[128 * 36];
    __shared__ float wsh[64 * 36];
    const int tid = threadIdx.x;
    const int row0 = blockIdx.x * 128;
    const int cg = tid & 7;
    const int rg = tid >> 3;

    float acc[8][8];
#pragma unroll
    for (int i = 0; i < 8; i++)
#pragma unroll
        for (int j = 0; j < 8; j++) acc[i][j] = 0.f;

    for (int kc = 0; kc < 384; kc += 32) {
#pragma unroll
        for (int i = 0; i < 8; i++) {
            int q = tid + i * 128;
            int r = q >> 3, kq = q & 7;
            float4 v = *(const float4*)(x + (row0 + r) * 384 + kc + kq * 4);
            *(float4*)(xs + r * 36 + kq * 4) = v;
        }
#pragma unroll
        for (int i = 0; i < 4; i++) {
            int q = tid + i * 128;
            int c = q >> 3, kq = q & 7;
            float4 v = *(const float4*)(dw + c * 384 + kc + kq * 4);
            *(float4*)(wsh + c * 36 + kq * 4) = v;
        }
        __syncthreads();
#pragma unroll
        for (int kq = 0; kq < 8; kq++) {
            float4 xv[8], wv[8];
#pragma unroll
            for (int j = 0; j < 8; j++)
                xv[j] = *(const float4*)(xs + (rg + 16 * j) * 36 + kq * 4);
#pragma unroll
            for (int i = 0; i < 8; i++)
                wv[i] = *(const float4*)(wsh + (cg + 8 * i) * 36 + kq * 4);
#pragma unroll
            for (int i = 0; i < 8; i++)
#pragma unroll
                for (int j = 0; j < 8; j++)
                    acc[i][j] += wv[i].x * xv[j].x + wv[i].y * xv[j].y +
                                 wv[i].z * xv[j].z + wv[i].w * xv[j].w;
        }
        __syncthreads();
    }

#pragma unroll
    for (int i = 0; i < 8; i++) {
        int c = cg + 8 * i;
        float bias = db[c];
#pragma unroll
        for (int j = 0; j < 8; j++) {
            int r = row0 + rg + 16 * j;
            int b = r >> 15;
            int t = (r >> 10) & 31;
            int l = r & 1023;
            h5[b * 2097152 + c * 32768 + t * 1024 + l] = gelu_f(acc[i][j] + bias);
        }
    }
}

// ---------------------------------------------------------------------------
// K2a: spatial depthwise (1,3,3) pad1 & (1,5,5) pad2 per (b,c,t) plane.
// 4096 blocks x 256 thr.
// ---------------------------------------------------------------------------
__global__ __launch_bounds__(256) void k2a_spatial(const float* __restrict__ h5,
                                                   const float* __restrict__ k31w,
                                                   const float* __restrict__ k31b,
                                                   const float* __restrict__ k51w,
                                                   const float* __restrict__ k51b,
                                                   float* __restrict__ a1,
                                                   float* __restrict__ a2) {
    __shared__ float pl[32 * 33];
    __shared__ float w3[9];
    __shared__ float w5[25];
    const int tid = threadIdx.x;
    const int bct = blockIdx.x;
    const int base = bct << 10;
    const int c = (bct >> 5) & 63;

#pragma unroll
    for (int i = 0; i < 4; i++) {
        int l = tid + i * 256;
        pl[(l >> 5) * 33 + (l & 31)] = h5[base + l];
    }
    if (tid < 9)  w3[tid] = k31w[c * 9 + tid];
    if (tid < 25) w5[tid] = k51w[c * 25 + tid];
    float b3 = k31b[c], b5 = k51b[c];
    __syncthreads();

#pragma unroll
    for (int i = 0; i < 4; i++) {
        int l = tid + i * 256;
        int h = l >> 5, w = l & 31;
        float s3 = b3;
#pragma unroll
        for (int dh = -1; dh <= 1; dh++) {
            int hh = h + dh;
            if (hh < 0 || hh > 31) continue;
#pragma unroll
            for (int dwi = -1; dwi <= 1; dwi++) {
                int ww = w + dwi;
                if (ww < 0 || ww > 31) continue;
                s3 += pl[hh * 33 + ww] * w3[(dh + 1) * 3 + dwi + 1];
            }
        }
        float s5 = b5;
#pragma unroll
        for (int dh = -2; dh <= 2; dh++) {
            int hh = h + dh;
            if (hh < 0 || hh > 31) continue;
#pragma unroll
            for (int dwi = -2; dwi <= 2; dwi++) {
                int ww = w + dwi;
                if (ww < 0 || ww > 31) continue;
                s5 += pl[hh * 33 + ww] * w5[(dh + 2) * 5 + dwi + 2];
            }
        }
        a1[base + l] = s3;
        a2[base + l] = s5;
    }
}

// ---------------------------------------------------------------------------
// K2b: FFT branch = complex circular conv along T (+ ifft(fb) delta at l==0),
// magnitude -> x3 (bf16). 512 blocks x 256 thr.
// ---------------------------------------------------------------------------
__global__ __launch_bounds__(256) void k2b_fft(const float* __restrict__ h5,
                                               __hip_bfloat16* __restrict__ x3,
                                               const float* __restrict__ gf) {
    __shared__ float col[32 * 256];
    __shared__ float gfs[128];
    const int tid = threadIdx.x;
    const int bid = blockIdx.x;
    const int bc = bid >> 2;
    const int l = (bid & 3) * 256 + tid;
    const int base = bc * 32768 + l;

    if (tid < 128) gfs[tid] = gf[tid];
#pragma unroll
    for (int t = 0; t < 32; t++) col[t * 256 + tid] = h5[base + t * 1024];
    __syncthreads();

    const bool dc = (l == 0);
    for (int t = 0; t < 32; t++) {
        float ar = dc ? gfs[64 + t] : 0.f;
        float ai = dc ? gfs[96 + t] : 0.f;
#pragma unroll
        for (int d = 0; d < 32; d++) {
            float xv = col[(((t - d) & 31) << 8) + tid];
            ar += xv * gfs[d];
            ai += xv * gfs[32 + d];
        }
        x3[base + t * 1024] = __float2bfloat16(sqrtf(ar * ar + ai * ai));
    }
}

// ---------------------------------------------------------------------------
// K2c: temporal depthwise convs (3,1,1) pad1 / (5,1,1) pad2, in-place a1/a2.
// 512 blocks x 256 thr; one T-column per thread.
// ---------------------------------------------------------------------------
__global__ __launch_bounds__(256) void k2c_temporal(float* __restrict__ a1,
                                                    float* __restrict__ a2,
                                                    const float* __restrict__ k32w,
                                                    const float* __restrict__ k32b,
                                                    const float* __restrict__ k52w,
                                                    const float* __restrict__ k52b) {
    const int cid = blockIdx.x * 256 + threadIdx.x;
    const int bc = cid >> 10;
    const int l = cid & 1023;
    const int c = bc & 63;
    const int base = bc * 32768 + l;

    float a[32];
#pragma unroll
    for (int t = 0; t < 32; t++) a[t] = a1[base + t * 1024];
    {
        float w0 = k32w[c * 3], w1 = k32w[c * 3 + 1], w2 = k32w[c * 3 + 2];
        float bb = k32b[c];
#pragma unroll
        for (int t = 0; t < 32; t++) {
            float v = bb + a[t] * w1;
            if (t > 0)  v += a[t - 1] * w0;
            if (t < 31) v += a[t + 1] * w2;
            a1[base + t * 1024] = v;
        }
    }
#pragma unroll
    for (int t = 0; t < 32; t++) a[t] = a2[base + t * 1024];
    {
        float u0 = k52w[c * 5], u1 = k52w[c * 5 + 1], u2 = k52w[c * 5 + 2];
        float u3 = k52w[c * 5 + 3], u4 = k52w[c * 5 + 4];
        float bb = k52b[c];
#pragma unroll
        for (int t = 0; t < 32; t++) {
            float v = bb + a[t] * u2;
            if (t > 1)  v += a[t - 2] * u0;
            if (t > 0)  v += a[t - 1] * u1;
            if (t < 31) v += a[t + 1] * u3;
            if (t < 30) v += a[t + 2] * u4;
            a2[base + t * 1024] = v;
        }
    }
}

// ---------------------------------------------------------------------------
// K2d: deterministic BN stats + finalize. One block per channel (64 x 256).
// ---------------------------------------------------------------------------
__global__ __launch_bounds__(256) void k2d_bn(const float* __restrict__ a1,
                                              const float* __restrict__ a2,
                                              const float* __restrict__ g3,
                                              const float* __restrict__ b3,
                                              const float* __restrict__ g5,
                                              const float* __restrict__ b5,
                                              float* __restrict__ bnp) {
    __shared__ float r0[256], r1[256], r2[256], r3[256];
    const int tid = threadIdx.x;
    const int c = blockIdx.x;
    float s1 = 0.f, q1 = 0.f, s2 = 0.f, q2 = 0.f;
#pragma unroll
    for (int b = 0; b < 2; b++) {
        const int base = b * 2097152 + c * 32768;
        for (int i = tid * 4; i < 32768; i += 1024) {
            float4 v1 = *(const float4*)(a1 + base + i);
            float4 v2 = *(const float4*)(a2 + base + i);
            s1 += v1.x + v1.y + v1.z + v1.w;
            q1 += v1.x * v1.x + v1.y * v1.y + v1.z * v1.z + v1.w * v1.w;
            s2 += v2.x + v2.y + v2.z + v2.w;
            q2 += v2.x * v2.x + v2.y * v2.y + v2.z * v2.z + v2.w * v2.w;
        }
    }
    r0[tid] = s1; r1[tid] = q1; r2[tid] = s2; r3[tid] = q2;
    __syncthreads();
    for (int s = 128; s > 0; s >>= 1) {
        if (tid < s) {
            r0[tid] += r0[tid + s];
            r1[tid] += r1[tid + s];
            r2[tid] += r2[tid + s];
            r3[tid] += r3[tid + s];
        }
        __syncthreads();
    }
    if (tid == 0) {
        const float inv_n = 1.0f / 65536.0f;
        float m1 = r0[0] * inv_n;
        float v1 = r1[0] * inv_n - m1 * m1;
        float sc1 = g3[c] * rsqrtf(v1 + 1e-5f);
        float m2 = r2[0] * inv_n;
        float v2 = r3[0] * inv_n - m2 * m2;
        float sc2 = g5[c] * rsqrtf(v2 + 1e-5f);
        bnp[c] = sc1;
        bnp[64 + c] = b3[c] - m1 * sc1;
        bnp[128 + c] = sc2;
        bnp[192 + c] = b5[c] - m2 * sc2;
    }
}

// ---------------------------------------------------------------------------
// K4: s = relu(bn(a1)) + relu(bn(a2)) + x3; attn = cw@s + cb; h5 += attn.
// 512 blocks x 256 thr; 128 positions x 64 ch per block.
// ---------------------------------------------------------------------------
__global__ __launch_bounds__(256) void k4_pointwise(float* __restrict__ h5,
                                                    const float* __restrict__ a1,
                                                    const float* __restrict__ a2,
                                                    const __hip_bfloat16* __restrict__ x3,
                                                    const float* __restrict__ cw,
                                                    const float* __restrict__ cb,
                                                    const float* __restrict__ bnp) {
    __shared__ float ls[64 * 129];
    __shared__ float cs[64 * 64];
    __shared__ float cbs[64];
    __shared__ float bns[256];
    const int tid = threadIdx.x;
    const int pos0 = blockIdx.x * 128;
    const int b = pos0 >> 15;
    const int rem = pos0 & 32767;
    const int t = rem >> 10;
    const int l0 = rem & 1023;
    const int pbase = b * 2097152 + t * 1024 + l0;

#pragma unroll
    for (int i = 0; i < 16; i++) cs[tid + i * 256] = cw[tid + i * 256];
    if (tid < 64) cbs[tid] = cb[tid];
    bns[tid] = bnp[tid];
    __syncthreads();

#pragma unroll
    for (int i = 0; i < 32; i++) {
        int q = tid + i * 256;
        int c = q >> 7, l = q & 127;
        int idx = pbase + c * 32768 + l;
        float v1 = fmaxf(bns[c] * a1[idx] + bns[64 + c], 0.f);
        float v2 = fmaxf(bns[128 + c] * a2[idx] + bns[192 + c], 0.f);
        ls[c * 129 + l] = v1 + v2 + __bfloat162float(x3[idx]);
    }
    __syncthreads();

    const int lidx = tid & 127;
    const int og = tid >> 7;
    float sreg[64];
#pragma unroll
    for (int c = 0; c < 64; c++) sreg[c] = ls[c * 129 + lidx];
    float acc[32];
#pragma unroll
    for (int oi = 0; oi < 32; oi++) acc[oi] = cbs[og * 32 + oi];
#pragma unroll
    for (int cq = 0; cq < 16; cq++) {
        float s0 = sreg[cq * 4], s1 = sreg[cq * 4 + 1];
        float s2 = sreg[cq * 4 + 2], s3 = sreg[cq * 4 + 3];
#pragma unroll
        for (int oi = 0; oi < 32; oi++) {
            float4 wv = *(const float4*)(cs + (og * 32 + oi) * 64 + cq * 4);
            acc[oi] += wv.x * s0 + wv.y * s1 + wv.z * s2 + wv.w * s3;
        }
    }
#pragma unroll
    for (int oi = 0; oi < 32; oi++) {
        int o = og * 32 + oi;
        int idx = pbase + o * 32768 + lidx;
        h5[idx] = h5[idx] + acc[oi];
    }
}

// ---------------------------------------------------------------------------
// K5: up GEMM + bias + GELU + residual -> FLOAT32 out.  (rewritten R5)
// grid (3, 1024) x 256 thr; 64 rows x 128 cols per block; 8 rows x 4 cols
// per thread. LDS: ys_t[row][k] and wts[c][k], both padded to 68 floats
// (gcd(68,32)=4 -> 4-way conflicts only; 272B stride keeps b128 aligned).
// Rolled K-loop (unroll 2) + explicit float4 components: no spills.
// ---------------------------------------------------------------------------
__global__ __launch_bounds__(256) void k5_up(const float* __restrict__ y5,
                                             const float* __restrict__ uw,
                                             const float* __restrict__ ub,
                                             const float* __restrict__ x,
                                             float* __restrict__ out) {
    __shared__ float ys_t[64 * 68];   // [row][k]
    __shared__ float wts[128 * 68];   // [c][k]
    const int tid = threadIdx.x;
    const int row0 = blockIdx.y * 64;
    const int c0 = blockIdx.x * 128;
    const int b = row0 >> 15;
    const int t = (row0 >> 10) & 31;
    const int l0 = row0 & 1023;
    const int ybase = b * 2097152 + t * 1024 + l0;

    // stage ys_t: 64 k x 64 r, global coalesced along r, LDS write stride 68
#pragma unroll
    for (int i = 0; i < 16; i++) {
        int e = tid + i * 256;
        int k = e >> 6, r = e & 63;
        ys_t[r * 68 + k] = y5[ybase + k * 32768 + r];
    }
    // stage wts: 128 c x 64 k, float4 both sides
#pragma unroll
    for (int i = 0; i < 8; i++) {
        int e = tid + i * 256;
        int c = e >> 4, k4 = e & 15;
        float4 v = *(const float4*)(uw + (c0 + c) * 64 + k4 * 4);
        *(float4*)(wts + c * 68 + k4 * 4) = v;
    }
    __syncthreads();

    const int cg = tid & 31;   // col lane: c = c0 + cg + 32*ci
    const int rg = tid >> 5;   // 0..7:     row = row0 + rg + 8*j
    float acc[8][4];
#pragma unroll
    for (int j = 0; j < 8; j++)
#pragma unroll
        for (int ci = 0; ci < 4; ci++) acc[j][ci] = 0.f;

#pragma unroll 2
    for (int kq = 0; kq < 16; kq++) {
        const int ko = kq * 4;
        float4 w0 = *(const float4*)(wts + (cg)      * 68 + ko);
        float4 w1 = *(const float4*)(wts + (cg + 32) * 68 + ko);
        float4 w2 = *(const float4*)(wts + (cg + 64) * 68 + ko);
        float4 w3 = *(const float4*)(wts + (cg + 96) * 68 + ko);
#pragma unroll
        for (int j = 0; j < 8; j++) {
            float4 yv = *(const float4*)(ys_t + (rg + 8 * j) * 68 + ko);
            acc[j][0] += yv.x * w0.x + yv.y * w0.y + yv.z * w0.z + yv.w * w0.w;
            acc[j][1] += yv.x * w1.x + yv.y * w1.y + yv.z * w1.z + yv.w * w1.w;
            acc[j][2] += yv.x * w2.x + yv.y * w2.y + yv.z * w2.z + yv.w * w2.w;
            acc[j][3] += yv.x * w3.x + yv.y * w3.y + yv.z * w3.z + yv.w * w3.w;
        }
    }

#pragma unroll
    for (int ci = 0; ci < 4; ci++) {
        int c = c0 + cg + 32 * ci;
        float ubv = ub[c];
#pragma unroll
        for (int j = 0; j < 8; j++) {
            int row = row0 + rg + 8 * j;
            float v = gelu_f(acc[j][ci] + ubv);
            out[row * 384 + c] = x[row * 384 + c] + v;
        }
    }
}

// ---------------------------------------------------------------------------
extern "C" void kernel_launch(void* const* d_in, const int* in_sizes, int n_in,
                              void* d_out, int out_size, void* d_ws, size_t ws_size,
                              hipStream_t stream) {
    const float* x      = (const float*)d_in[0];
    const float* down_w = (const float*)d_in[1];
    const float* down_b = (const float*)d_in[2];
    const float* k31w   = (const float*)d_in[3];
    const float* k31b   = (const float*)d_in[4];
    const float* k32w   = (const float*)d_in[5];
    const float* k32b   = (const float*)d_in[6];
    const float* bn3g   = (const float*)d_in[7];
    const float* bn3b   = (const float*)d_in[8];
    const float* k51w   = (const float*)d_in[9];
    const float* k51b   = (const float*)d_in[10];
    const float* k52w   = (const float*)d_in[11];
    const float* k52b   = (const float*)d_in[12];
    const float* bn5g   = (const float*)d_in[13];
    const float* bn5b   = (const float*)d_in[14];
    const float* conv_w = (const float*)d_in[15];
    const float* conv_b = (const float*)d_in[16];
    const float* fw     = (const float*)d_in[17];
    const float* fb     = (const float*)d_in[18];
    const float* up_w   = (const float*)d_in[19];
    const float* up_b   = (const float*)d_in[20];
    float* out = (float*)d_out;

    float* wsf = (float*)d_ws;
    float* gfb = wsf + OFF_GF;
    float* bnp = wsf + OFF_BN;
    float* h5  = wsf + OFF_H5;
    float* a1  = wsf + OFF_A1;
    float* a2  = wsf + OFF_A2;
    __hip_bfloat16* x3 = (__hip_bfloat16*)(wsf + OFF_X3);

    k0_prep<<<1, 64, 0, stream>>>(fw, fb, gfb);
    k1_down<<<512, 128, 0, stream>>>(x, down_w, down_b, h5);
    k2a_spatial<<<4096, 256, 0, stream>>>(h5, k31w, k31b, k51w, k51b, a1, a2);
    k2b_fft<<<512, 256, 0, stream>>>(h5, x3, gfb);
    k2c_temporal<<<512, 256, 0, stream>>>(a1, a2, k32w, k32b, k52w, k52b);
    k2d_bn<<<64, 256, 0, stream>>>(a1, a2, bn3g, bn3b, bn5g, bn5b, bnp);
    k4_pointwise<<<512, 256, 0, stream>>>(h5, a1, a2, x3, conv_w, conv_b, bnp);
    k5_up<<<dim3(3, 1024), 256, 0, stream>>>(h5, up_w, up_b, x, out);
}